// Round 12
// baseline (395.633 us; speedup 1.0000x reference)
//
#include <hip/hip_runtime.h>
#include <hip/hip_fp16.h>

#define S_N 50000
#define E_N 20000
#define K_N 128
#define B_N 16384
#define NE_N 1000000

#define S_PER_XCD 6250   // S_N/8
#define E_PER_XCD 2500   // E_N/8

// padded-CSR capacities (degree ~ Poisson: S mean 40 sd 6.3, E mean 100 sd 10)
#define SCAP 96
#define ECAP 176

// sub-bucketed CSR build: 32 sub-buckets per XCD per side
#define NBKT 512
#define S_SUB 196        // ceil(6250/32)
#define E_SUB 79         // ceil(2500/32)
#define BKCAP 8704       // mean ~7850, sd ~89 -> +9.6 sigma

typedef short bf16x8 __attribute__((ext_vector_type(8)));
typedef float f32x4 __attribute__((ext_vector_type(4)));
typedef int i32x4 __attribute__((ext_vector_type(4)));
typedef float f32x4v __attribute__((ext_vector_type(4)));
typedef unsigned u32x4 __attribute__((ext_vector_type(4)));

__device__ __forceinline__ float sigmoidf_(float v) {
    return 1.0f / (1.0f + __expf(-v));
}
__device__ __forceinline__ float tanh_fast(float v) {
    float e = __expf(2.0f * v);
    return 1.0f - 2.0f / (e + 1.0f);
}
__device__ __forceinline__ unsigned short f2bf(float v) {
    unsigned u = __float_as_uint(v);
    u += 0x7fffu + ((u >> 16) & 1u);
    return (unsigned short)(u >> 16);
}
__device__ __forceinline__ void split_bf(float v, unsigned short& hi, unsigned short& lo) {
    unsigned u = __float_as_uint(v);
    hi = (unsigned short)(u >> 16);
    float fh = __uint_as_float(u & 0xffff0000u);
    lo = f2bf(v - fh);
}
// unpack a u32 holding 2 halves
__device__ __forceinline__ float2 h2f2(unsigned u) {
    __half2 h = *(const __half2*)&u;
    return __half22float2(h);
}
// accumulate 8 halves (one uint4) scaled by v into acc[0..7]
__device__ __forceinline__ void accum8(float* acc, uint4 h, float v) {
    float2 p0 = h2f2(h.x);
    float2 p1 = h2f2(h.y);
    float2 p2 = h2f2(h.z);
    float2 p3 = h2f2(h.w);
    acc[0] = fmaf(v, p0.x, acc[0]); acc[1] = fmaf(v, p0.y, acc[1]);
    acc[2] = fmaf(v, p1.x, acc[2]); acc[3] = fmaf(v, p1.y, acc[3]);
    acc[4] = fmaf(v, p2.x, acc[4]); acc[5] = fmaf(v, p2.y, acc[5]);
    acc[6] = fmaf(v, p3.x, acc[6]); acc[7] = fmaf(v, p3.y, acc[7]);
}
__device__ __forceinline__ unsigned f2h2u(float a, float b) {
    __half2 h = __floats2half2_rn(a, b);
    return *(const unsigned*)&h;
}

// ---- CSR build phase 1: single-read, 512-way sub-bucketize --------------
// R17 structure (LDS-hist rank + one global claim per (block,bucket));
// R18 sizing (1024-thr x 8 edges -> ~256B runs per bucket). R22: buckets
// are now a FRESH region (no statAH overlay) so the fused scatter+gather
// can write statAH while other blocks still read their buckets.
__global__ __launch_bounds__(1024) void bucketize2(
    const i32x4* __restrict__ r1, const i32x4* __restrict__ c1,
    const f32x4v* __restrict__ vui1, const f32x4v* __restrict__ viu1,
    const i32x4* __restrict__ r0, const i32x4* __restrict__ c0,
    const f32x4v* __restrict__ vui0, const f32x4v* __restrict__ viu0,
    unsigned long long* __restrict__ buck, int* __restrict__ gcur) {
    __shared__ int hist[NBKT];
    __shared__ int base[NBKT];
    const int tid = threadIdx.x;
    for (int b = tid; b < NBKT; b += 1024) hist[b] = 0;
    __syncthreads();
    const int NV = NE_N / 4;          // 250000 vectors per relation
    i32x4 rv[2], cv[2]; f32x4v av[2], bv[2];
    int bkt[16], lr[16];
#pragma unroll
    for (int rep = 0; rep < 2; ++rep) {
        int i = blockIdx.x * 2048 + rep * 1024 + tid;
        bool valid = i < 2 * NV;
        if (valid) {
            if (i < NV) {
                rv[rep] = __builtin_nontemporal_load(r1 + i);
                cv[rep] = __builtin_nontemporal_load(c1 + i);
                av[rep] = __builtin_nontemporal_load(vui1 + i);
                bv[rep] = __builtin_nontemporal_load(viu1 + i);
            } else {
                int j = i - NV;
                rv[rep] = __builtin_nontemporal_load(r0 + j);
                cv[rep] = __builtin_nontemporal_load(c0 + j);
                av[rep] = __builtin_nontemporal_load(vui0 + j);
                bv[rep] = __builtin_nontemporal_load(viu0 + j);
            }
        }
#pragma unroll
        for (int k = 0; k < 4; ++k) {
            int u = rep * 8 + k * 2;
            if (valid) {
                int r = rv[rep][k], c = cv[rep][k];
                int xs = r / S_PER_XCD;
                int ss = (r - xs * S_PER_XCD) / S_SUB;
                int xe = c / E_PER_XCD;
                int se = (c - xe * E_PER_XCD) / E_SUB;
                bkt[u] = ss * 8 + xs;
                bkt[u + 1] = 256 + se * 8 + xe;
                lr[u] = atomicAdd(&hist[bkt[u]], 1);
                lr[u + 1] = atomicAdd(&hist[bkt[u + 1]], 1);
            } else {
                bkt[u] = -1; bkt[u + 1] = -1;
            }
        }
    }
    __syncthreads();
    for (int b = tid; b < NBKT; b += 1024) {
        int h = hist[b];
        base[b] = h ? atomicAdd(&gcur[b], h) : 0;
    }
    __syncthreads();
#pragma unroll
    for (int rep = 0; rep < 2; ++rep) {
#pragma unroll
        for (int k = 0; k < 4; ++k) {
            int u = rep * 8 + k * 2;
            if (bkt[u] >= 0) {
                int r = rv[rep][k], c = cv[rep][k];
                unsigned entS = ((unsigned)f2bf(av[rep][k]) << 16) | (unsigned)c;
                unsigned entE = ((unsigned)f2bf(bv[rep][k]) << 16) | (unsigned)r;
                int pS = base[bkt[u]] + lr[u];
                int pE = base[bkt[u + 1]] + lr[u + 1];
                if (pS < BKCAP)
                    buck[(size_t)bkt[u] * BKCAP + pS] =
                        ((unsigned long long)(unsigned)r << 32) | entS;
                if (pE < BKCAP)
                    buck[(size_t)bkt[u + 1] * BKCAP + pE] =
                        ((unsigned long long)(unsigned)c << 32) | entE;
            }
        }
    }
}

// mark nodes referenced by the batch (both sides, one launch)
__global__ __launch_bounds__(256) void mark_needed2(
    const int* __restrict__ sid, const int* __restrict__ eid,
    unsigned* __restrict__ maskS, unsigned* __restrict__ maskE) {
    int i = blockIdx.x * blockDim.x + threadIdx.x;
    if (i < B_N) {
        int v = sid[i];
        atomicOr(&maskS[v >> 5], 1u << (v & 31));
    } else if (i < 2 * B_N) {
        int v = eid[i - B_N];
        atomicOr(&maskE[v >> 5], 1u << (v & 31));
    }
}

// ---- fp32 embeddings -> fp16 tables + counter/mask/cursor zero-init -----
__global__ __launch_bounds__(256) void cvt_f16_init(
    const float2* __restrict__ sE, const float2* __restrict__ eE,
    __half2* __restrict__ sH, __half2* __restrict__ eH,
    int* __restrict__ cntS, int* __restrict__ cntE,
    unsigned* __restrict__ maskS, unsigned* __restrict__ maskE,
    int* __restrict__ cur) {
    int i = blockIdx.x * 256 + threadIdx.x;
    if (i < S_N) cntS[i] = 0;
    if (i < E_N) cntE[i] = 0;
    if (i < 2048) maskS[i] = 0;
    if (i < 1024) maskE[i] = 0;
    if (i < NBKT) cur[i] = 0;
    const int nS = S_N * 64;
    if (i < nS) {
        float2 v = sE[i];
        sH[i] = __floats2half2_rn(v.x, v.y);
    } else {
        int j = i - nS;
        if (j < E_N * 64) {
            float2 v = eE[j];
            eH[j] = __floats2half2_rn(v.x, v.y);
        }
    }
}

// ---- propagation row body with n given: wave = 1 dest row; slot(lane>>4)
// = 1 of 4 edges in flight, seg(lane&15) = 16 B of the 256 B row. 16 edges
// in flight (R18). NT self/dst (R21, neutral-kept).
__device__ __forceinline__ void gather_row_n(
    const uint4* __restrict__ src, const uint4* __restrict__ self,
    const float* __restrict__ dA, const float* __restrict__ dB,
    const unsigned* __restrict__ csr,
    uint4* __restrict__ dst, int cap, int w, int lane, int n) {
    int slot = lane >> 4;
    int seg = lane & 15;
    const unsigned* cbase = csr + (size_t)w * cap;
    float acc[8] = {};
    int i = 0;
    for (; i + 16 <= n; i += 16) {
        unsigned qa = __builtin_nontemporal_load(cbase + i + slot);
        unsigned qb = __builtin_nontemporal_load(cbase + i + 4 + slot);
        unsigned qc = __builtin_nontemporal_load(cbase + i + 8 + slot);
        unsigned qd = __builtin_nontemporal_load(cbase + i + 12 + slot);
        uint4 ha = src[(size_t)(qa & 0xffffu) * 16 + seg];
        uint4 hb = src[(size_t)(qb & 0xffffu) * 16 + seg];
        uint4 hc = src[(size_t)(qc & 0xffffu) * 16 + seg];
        uint4 hd = src[(size_t)(qd & 0xffffu) * 16 + seg];
        accum8(acc, ha, __uint_as_float(qa & 0xffff0000u));
        accum8(acc, hb, __uint_as_float(qb & 0xffff0000u));
        accum8(acc, hc, __uint_as_float(qc & 0xffff0000u));
        accum8(acc, hd, __uint_as_float(qd & 0xffff0000u));
    }
    for (; i + 8 <= n; i += 8) {
        unsigned qa = __builtin_nontemporal_load(cbase + i + slot);
        unsigned qb = __builtin_nontemporal_load(cbase + i + 4 + slot);
        uint4 ha = src[(size_t)(qa & 0xffffu) * 16 + seg];
        uint4 hb = src[(size_t)(qb & 0xffffu) * 16 + seg];
        accum8(acc, ha, __uint_as_float(qa & 0xffff0000u));
        accum8(acc, hb, __uint_as_float(qb & 0xffff0000u));
    }
    for (; i < n; i += 4) {
        int e = i + slot;
        if (e < n) {
            unsigned q = __builtin_nontemporal_load(cbase + e);
            uint4 h = src[(size_t)(q & 0xffffu) * 16 + seg];
            accum8(acc, h, __uint_as_float(q & 0xffff0000u));
        }
    }
#pragma unroll
    for (int j = 0; j < 8; ++j) {
        acc[j] += __shfl_xor(acc[j], 16);
        acc[j] += __shfl_xor(acc[j], 32);
    }
    if (slot == 0) {
        u32x4 hsv = __builtin_nontemporal_load(
            reinterpret_cast<const u32x4*>(self) + ((size_t)w * 16 + seg));
        unsigned h0 = hsv[0], h1 = hsv[1], h2 = hsv[2], h3 = hsv[3];
        float d = dA[w] + dB[w];
        float2 s0 = h2f2(h0);
        float2 s1 = h2f2(h1);
        float2 s2 = h2f2(h2);
        float2 s3 = h2f2(h3);
        u32x4 o;
        o[0] = f2h2u(fmaf(s0.x, d, acc[0]), fmaf(s0.y, d, acc[1]));
        o[1] = f2h2u(fmaf(s1.x, d, acc[2]), fmaf(s1.y, d, acc[3]));
        o[2] = f2h2u(fmaf(s2.x, d, acc[4]), fmaf(s2.y, d, acc[5]));
        o[3] = f2h2u(fmaf(s3.x, d, acc[6]), fmaf(s3.y, d, acc[7]));
        __builtin_nontemporal_store(
            o, reinterpret_cast<u32x4*>(dst) + ((size_t)w * 16 + seg));
    }
}

// ---- R22: fused CSR-scatter + layer-1 gather. One WG per sub-bucket
// (1024 thr = 16 waves -> 32 waves/CU, vs scatter2's 8). Phase 1 builds
// this block's node-range CSR (LDS slot counters, XCD-local stores);
// phase 2's waves immediately gather those rows -- CSR still L2-hot, row
// counts read from LDS, scatter store latency overlaps gather misses.
__global__ __launch_bounds__(1024) void scatter_gather(
    const unsigned long long* __restrict__ buck, const int* __restrict__ gcur,
    int* __restrict__ cntS, int* __restrict__ cntE,
    unsigned* __restrict__ csrS, unsigned* __restrict__ csrE,
    const uint4* __restrict__ sEH, const uint4* __restrict__ eEH,
    const float* __restrict__ d_i_1, const float* __restrict__ d_i_0,
    const float* __restrict__ d_j_1, const float* __restrict__ d_j_0,
    uint4* __restrict__ statAH, uint4* __restrict__ kdiffAH) {
    __shared__ int lcnt[S_SUB];
    const int bid = blockIdx.x;
    const int tid = threadIdx.x;
    const bool isS = bid < 256;
    const int x = bid & 7;
    const int s = (isS ? bid : bid - 256) >> 3;
    const int start = isS ? x * S_PER_XCD + s * S_SUB : x * E_PER_XCD + s * E_SUB;
    const int len = isS ? min(S_SUB, S_PER_XCD - s * S_SUB)
                        : min(E_SUB, E_PER_XCD - s * E_SUB);
    const int cap = isS ? SCAP : ECAP;
    unsigned* csr = isS ? csrS : csrE;
    for (int l = tid; l < len; l += 1024) lcnt[l] = 0;
    __syncthreads();
    int n = gcur[bid];
    if (n > BKCAP) n = BKCAP;
    const unsigned long long* bp = buck + (size_t)bid * BKCAP;
    for (int i = tid; i < n; i += 1024) {
        unsigned long long v = __builtin_nontemporal_load(bp + i);
        int node = (int)(v >> 32);
        unsigned entry = (unsigned)v;
        int slot = atomicAdd(&lcnt[node - start], 1);
        if (slot < cap) csr[(size_t)node * cap + slot] = entry;
    }
    __syncthreads();
    // global per-node counts for the (masked) layer-2 gather
    for (int l = tid; l < len; l += 1024) {
        int c = min(lcnt[l], cap);
        if (isS) cntS[start + l] = c;
        else     cntE[start + l] = c;
    }
    // phase 2: layer-1 gather of this block's own rows (CSR is L2-hot)
    const int wave = tid >> 6;
    const int lane = tid & 63;
    const uint4* src  = isS ? eEH : sEH;
    const uint4* self = isS ? sEH : eEH;
    const float* dA = isS ? d_i_1 : d_j_1;
    const float* dB = isS ? d_i_0 : d_j_0;
    uint4* dst = isS ? statAH : kdiffAH;
    for (int r = wave; r < len; r += 16) {
        int nn = min(lcnt[r], cap);
        gather_row_n(src, self, dA, dB, csr, dst, cap, start + r, lane, nn);
    }
}

// ---- layer-2 fused S+E gather (masked). E blocks first: long ~100-edge
// E rows start early, short S rows fill the tail. (R20)
__device__ __forceinline__ void gather_row(
    const uint4* __restrict__ src, const uint4* __restrict__ self,
    const float* __restrict__ dA, const float* __restrict__ dB,
    const int* __restrict__ cnt, const unsigned* __restrict__ csr,
    const unsigned* __restrict__ need,
    uint4* __restrict__ dst, int nrow, int cap, int w, int lane) {
    if (w >= nrow) return;
    if (need && !((need[w >> 5] >> (w & 31)) & 1u)) return;
    int n = cnt[w];
    if (n > cap) n = cap;
    gather_row_n(src, self, dA, dB, csr, dst, cap, w, lane, n);
}

__global__ __launch_bounds__(256) void gather_dual(
    const uint4* __restrict__ srcE, const uint4* __restrict__ selfE,
    const float* __restrict__ dEA, const float* __restrict__ dEB,
    const int* __restrict__ cntEp, const unsigned* __restrict__ csrEp,
    const unsigned* __restrict__ needE, uint4* __restrict__ dstE,
    const uint4* __restrict__ srcS, const uint4* __restrict__ selfS,
    const float* __restrict__ dSA, const float* __restrict__ dSB,
    const int* __restrict__ cntSp, const unsigned* __restrict__ csrSp,
    const unsigned* __restrict__ needS, uint4* __restrict__ dstS,
    int eBlocks) {
    int lane = threadIdx.x & 63;
    int sub = threadIdx.x >> 6;
    if ((int)blockIdx.x < eBlocks) {
        int w = blockIdx.x * 4 + sub;
        gather_row(srcE, selfE, dEA, dEB, cntEp, csrEp, needE, dstE,
                   E_N, ECAP, w, lane);
    } else {
        int w = (blockIdx.x - eBlocks) * 4 + sub;
        gather_row(srcS, selfS, dSA, dSB, cntSp, csrSp, needS, dstS,
                   S_N, SCAP, w, lane);
    }
}

// ---- prediction stage 1+0 fused: feature x -> split bf16, and |W| ->
// split bf16 tables (blocks >= featBlocks). (R21)
__global__ __launch_bounds__(256) void feature_abs_kernel(
    const int* __restrict__ stu_id, const int* __restrict__ ex_id,
    const float* __restrict__ ikp,
    const __half2* __restrict__ statH, const __half2* __restrict__ kdiffH,
    const float* __restrict__ s_bias, const float* __restrict__ e_disc,
    unsigned short* __restrict__ xhi, unsigned short* __restrict__ xlo,
    const float* __restrict__ W1, const float* __restrict__ W2,
    unsigned short* __restrict__ w1hi, unsigned short* __restrict__ w1lo,
    unsigned short* __restrict__ w2hi, unsigned short* __restrict__ w2lo,
    int featBlocks) {
    if ((int)blockIdx.x >= featBlocks) {
        int i = (blockIdx.x - featBlocks) * 256 + threadIdx.x;
        unsigned short hi, lo;
        if (i < 32768) {
            split_bf(fabsf(W1[i]), hi, lo);
            w1hi[i] = hi; w1lo[i] = lo;
        } else {
            int j = i - 32768;
            split_bf(fabsf(W2[j]), hi, lo);
            w2hi[j] = hi; w2lo[j] = lo;
        }
        return;
    }
    int i = blockIdx.x * 256 + threadIdx.x;
    int row = i >> 5;
    int k4 = (i & 31) * 4;
    int s = stu_id[row];
    int e = ex_id[row];
    float sb = s_bias[s];
    float ed = sigmoidf_(e_disc[e]);
    float2 s01 = __half22float2(statH[(size_t)s * 64 + (k4 >> 1)]);
    float2 s23 = __half22float2(statH[(size_t)s * 64 + (k4 >> 1) + 1]);
    float2 k01 = __half22float2(kdiffH[(size_t)e * 64 + (k4 >> 1)]);
    float2 k23 = __half22float2(kdiffH[(size_t)e * 64 + (k4 >> 1) + 1]);
    float4 iv = *(const float4*)(ikp + (size_t)row * K_N + k4);
    float f0 = iv.x * (sigmoidf_(s01.x + sb) - sigmoidf_(k01.x)) * ed;
    float f1 = iv.y * (sigmoidf_(s01.y + sb) - sigmoidf_(k01.y)) * ed;
    float f2 = iv.z * (sigmoidf_(s23.x + sb) - sigmoidf_(k23.x)) * ed;
    float f3 = iv.w * (sigmoidf_(s23.y + sb) - sigmoidf_(k23.y)) * ed;
    ushort4 oh, ol;
    split_bf(f0, oh.x, ol.x);
    split_bf(f1, oh.y, ol.y);
    split_bf(f2, oh.z, ol.z);
    split_bf(f3, oh.w, ol.w);
    *(ushort4*)(xhi + (size_t)row * K_N + k4) = oh;
    *(ushort4*)(xlo + (size_t)row * K_N + k4) = ol;
}

// ---- prediction stage 2: split-bf16 MFMA MLP ----------------------------
#define H1S 264

__global__ __launch_bounds__(256) void mlp_mfma(
    const unsigned short* __restrict__ xhi, const unsigned short* __restrict__ xlo,
    const unsigned short* __restrict__ w1hi, const unsigned short* __restrict__ w1lo,
    const unsigned short* __restrict__ w2hi, const unsigned short* __restrict__ w2lo,
    const float* __restrict__ b1, const float* __restrict__ b2,
    const float* __restrict__ W3, const float* __restrict__ b3,
    float* __restrict__ out) {
    __shared__ unsigned short h1hi[32 * H1S];
    __shared__ unsigned short h1lo[32 * H1S];
    __shared__ float partial[4][32];

    const int t = threadIdx.x;
    const int lane = t & 63;
    const int w = t >> 6;
    const int l15 = lane & 15;
    const int quad = lane >> 4;
    const int r0 = blockIdx.x * 32;

    f32x4 acc1[2][4] = {};
    for (int ks = 0; ks < 128; ks += 32) {
        bf16x8 ah[2], al[2], bh[4], bl[4];
#pragma unroll
        for (int mt = 0; mt < 2; ++mt) {
            size_t o = (size_t)(r0 + mt * 16 + l15) * K_N + ks + quad * 8;
            ah[mt] = *(const bf16x8*)(xhi + o);
            al[mt] = *(const bf16x8*)(xlo + o);
        }
#pragma unroll
        for (int nt = 0; nt < 4; ++nt) {
            size_t o = (size_t)(w * 64 + nt * 16 + l15) * 128 + ks + quad * 8;
            bh[nt] = *(const bf16x8*)(w1hi + o);
            bl[nt] = *(const bf16x8*)(w1lo + o);
        }
#pragma unroll
        for (int mt = 0; mt < 2; ++mt)
#pragma unroll
            for (int nt = 0; nt < 4; ++nt) {
                acc1[mt][nt] = __builtin_amdgcn_mfma_f32_16x16x32_bf16(
                    ah[mt], bh[nt], acc1[mt][nt], 0, 0, 0);
                acc1[mt][nt] = __builtin_amdgcn_mfma_f32_16x16x32_bf16(
                    ah[mt], bl[nt], acc1[mt][nt], 0, 0, 0);
                acc1[mt][nt] = __builtin_amdgcn_mfma_f32_16x16x32_bf16(
                    al[mt], bh[nt], acc1[mt][nt], 0, 0, 0);
            }
    }
#pragma unroll
    for (int nt = 0; nt < 4; ++nt) {
        int c = w * 64 + nt * 16 + l15;
        float bias = b1[c];
#pragma unroll
        for (int mt = 0; mt < 2; ++mt)
#pragma unroll
            for (int rg = 0; rg < 4; ++rg) {
                int row = mt * 16 + quad * 4 + rg;
                float h = tanh_fast(acc1[mt][nt][rg] + bias);
                unsigned short hi, lo;
                split_bf(h, hi, lo);
                h1hi[row * H1S + c] = hi;
                h1lo[row * H1S + c] = lo;
            }
    }
    __syncthreads();

    f32x4 acc2[2][2] = {};
    for (int ks = 0; ks < 256; ks += 32) {
        bf16x8 ah[2], al[2], bh[2], bl[2];
#pragma unroll
        for (int mt = 0; mt < 2; ++mt) {
            int o = (mt * 16 + l15) * H1S + ks + quad * 8;
            ah[mt] = *(const bf16x8*)(&h1hi[o]);
            al[mt] = *(const bf16x8*)(&h1lo[o]);
        }
#pragma unroll
        for (int nt = 0; nt < 2; ++nt) {
            size_t o = (size_t)(w * 32 + nt * 16 + l15) * 256 + ks + quad * 8;
            bh[nt] = *(const bf16x8*)(w2hi + o);
            bl[nt] = *(const bf16x8*)(w2lo + o);
        }
#pragma unroll
        for (int mt = 0; mt < 2; ++mt)
#pragma unroll
            for (int nt = 0; nt < 2; ++nt) {
                acc2[mt][nt] = __builtin_amdgcn_mfma_f32_16x16x32_bf16(
                    ah[mt], bh[nt], acc2[mt][nt], 0, 0, 0);
                acc2[mt][nt] = __builtin_amdgcn_mfma_f32_16x16x32_bf16(
                    ah[mt], bl[nt], acc2[mt][nt], 0, 0, 0);
                acc2[mt][nt] = __builtin_amdgcn_mfma_f32_16x16x32_bf16(
                    al[mt], bh[nt], acc2[mt][nt], 0, 0, 0);
            }
    }

    float w3v[2], b2v[2];
#pragma unroll
    for (int nt = 0; nt < 2; ++nt) {
        int c = w * 32 + nt * 16 + l15;
        w3v[nt] = fabsf(W3[c]);
        b2v[nt] = b2[c];
    }
#pragma unroll
    for (int mt = 0; mt < 2; ++mt)
#pragma unroll
        for (int rg = 0; rg < 4; ++rg) {
            float v = w3v[0] * tanh_fast(acc2[mt][0][rg] + b2v[0]) +
                      w3v[1] * tanh_fast(acc2[mt][1][rg] + b2v[1]);
            v += __shfl_xor(v, 1, 16);
            v += __shfl_xor(v, 2, 16);
            v += __shfl_xor(v, 4, 16);
            v += __shfl_xor(v, 8, 16);
            if (l15 == 0) partial[w][mt * 16 + quad * 4 + rg] = v;
        }
    __syncthreads();
    if (t < 32) {
        float v = partial[0][t] + partial[1][t] + partial[2][t] + partial[3][t];
        out[r0 + t] = sigmoidf_(v + b3[0]);
    }
}

extern "C" void kernel_launch(void* const* d_in, const int* in_sizes, int n_in,
                              void* d_out, int out_size, void* d_ws, size_t ws_size,
                              hipStream_t stream) {
    const int* stu_id        = (const int*)d_in[0];
    const int* input_ex      = (const int*)d_in[1];
    const float* ikp         = (const float*)d_in[2];
    const int* rows_1        = (const int*)d_in[3];
    const int* cols_1        = (const int*)d_in[4];
    const int* rows_0        = (const int*)d_in[5];
    const int* cols_0        = (const int*)d_in[6];
    const float* vals_ui_1   = (const float*)d_in[7];
    const float* vals_iu_1   = (const float*)d_in[8];
    const float* vals_ui_0   = (const float*)d_in[9];
    const float* vals_iu_0   = (const float*)d_in[10];
    const float* d_i_1       = (const float*)d_in[11];
    const float* d_j_1       = (const float*)d_in[12];
    const float* d_i_0       = (const float*)d_in[13];
    const float* d_j_0       = (const float*)d_in[14];
    const float* student_emb = (const float*)d_in[15];
    const float* exercise_emb= (const float*)d_in[16];
    const float* s_bias      = (const float*)d_in[17];
    const float* e_disc      = (const float*)d_in[18];
    const float* W1          = (const float*)d_in[19];
    const float* b1          = (const float*)d_in[20];
    const float* W2          = (const float*)d_in[21];
    const float* b2          = (const float*)d_in[22];
    const float* W3          = (const float*)d_in[23];
    const float* b3          = (const float*)d_in[24];

    // ---- workspace layout (fp16 tables, 4 B packed padded CSR) ----
    // R22: buckets are FRESH (35.7 MB) -- no statAH overlay -- so the
    // fused scatter+gather can write statAH/kdiffAH while other blocks
    // still read buckets. Total ws ~105 MB.
    char* p = (char*)d_ws;
    __half2* sEH     = (__half2*)p; p += (size_t)S_N * K_N * 2;   // inputs; reused as statBH
    __half2* eEH     = (__half2*)p; p += (size_t)E_N * K_N * 2;   // inputs; reused as kdiffBH
    __half2* statAH  = (__half2*)p; p += (size_t)S_N * K_N * 2;   // also xhi/xlo overlay
    __half2* kdiffAH = (__half2*)p; p += (size_t)E_N * K_N * 2;   // also weight overlay
    unsigned* csrS = (unsigned*)p; p += (size_t)S_N * SCAP * 4;   // 19.2 MB
    unsigned* csrE = (unsigned*)p; p += (size_t)E_N * ECAP * 4;   // 14.1 MB
    int* cntS     = (int*)p;   p += (size_t)S_N * 4;
    int* cntE     = (int*)p;   p += (size_t)E_N * 4;
    unsigned* maskS = (unsigned*)p; p += 2048 * 4;
    unsigned* maskE = (unsigned*)p; p += 1024 * 4;
    int* cur      = (int*)p;   p += NBKT * 4;
    p = (char*)(((size_t)p + 255) & ~(size_t)255);
    unsigned long long* buck = (unsigned long long*)p;            // 512 buckets, fresh
    p += (size_t)NBKT * BKCAP * 8;
    __half2* statBH  = sEH;
    __half2* kdiffBH = eEH;
    unsigned short* xhi = (unsigned short*)statAH;
    unsigned short* xlo = xhi + (size_t)B_N * K_N;
    unsigned short* w1hi = (unsigned short*)kdiffAH;
    unsigned short* w1lo = w1hi + 32768;
    unsigned short* w2hi = w1lo + 32768;
    unsigned short* w2lo = w2hi + 32768;

    // ---- fp16 tables + zero-init ----
    cvt_f16_init<<<((S_N + E_N) * 64 + 255) / 256, 256, 0, stream>>>(
        (const float2*)student_emb, (const float2*)exercise_emb, sEH, eEH,
        cntS, cntE, maskS, maskE, cur);

    // ---- CSR build phase 1: single-read 512-way bucketize ----
    const int bkBlocks = (2 * NE_N / 4 + 2047) / 2048;   // 245 x 1024 threads
    bucketize2<<<bkBlocks, 1024, 0, stream>>>(
        (const i32x4*)rows_1, (const i32x4*)cols_1,
        (const f32x4v*)vals_ui_1, (const f32x4v*)vals_iu_1,
        (const i32x4*)rows_0, (const i32x4*)cols_0,
        (const f32x4v*)vals_ui_0, (const f32x4v*)vals_iu_0,
        buck, cur);

    // ---- needed-row masks (for layer 2) ----
    mark_needed2<<<(2 * B_N + 255) / 256, 256, 0, stream>>>(
        stu_id, input_ex, maskS, maskE);

    // ---- fused: per-sub-bucket CSR scatter + layer-1 gather ----
    scatter_gather<<<NBKT, 1024, 0, stream>>>(
        buck, cur, cntS, cntE, csrS, csrE,
        (const uint4*)sEH, (const uint4*)eEH,
        d_i_1, d_i_0, d_j_1, d_j_0,
        (uint4*)statAH, (uint4*)kdiffAH);

    const int sGrid = (S_N + 3) / 4;    // 12500
    const int eGrid = (E_N + 3) / 4;    // 5000

    // ---- layer 2: fused E+S gather (masked; inputs dead now) ----
    gather_dual<<<eGrid + sGrid, 256, 0, stream>>>(
        (const uint4*)statAH, (const uint4*)kdiffAH, d_j_1, d_j_0,
        cntE, csrE, maskE, (uint4*)kdiffBH,
        (const uint4*)kdiffAH, (const uint4*)statAH, d_i_1, d_i_0,
        cntS, csrS, maskS, (uint4*)statBH, eGrid);

    // ---- prediction: fused feature+abs -> split bf16, MFMA MLP ----
    const int featBlocks = B_N * 32 / 256;   // 2048
    feature_abs_kernel<<<featBlocks + 256, 256, 0, stream>>>(
        stu_id, input_ex, ikp, statBH, kdiffBH, s_bias, e_disc, xhi, xlo,
        W1, W2, w1hi, w1lo, w2hi, w2lo, featBlocks);
    mlp_mfma<<<B_N / 32, 256, 0, stream>>>(xhi, xlo, w1hi, w1lo, w2hi, w2lo,
                                           b1, b2, W3, b3, (float*)d_out);
}

// Round 13
// 380.435 us; speedup vs baseline: 1.0399x; 1.0399x over previous
//
#include <hip/hip_runtime.h>
#include <hip/hip_fp16.h>

#define S_N 50000
#define E_N 20000
#define K_N 128
#define B_N 16384
#define NE_N 1000000

#define S_PER_XCD 6250   // S_N/8
#define E_PER_XCD 2500   // E_N/8

// padded-CSR capacities (degree ~ Poisson: S mean 40 sd 6.3, E mean 100 sd 10)
#define SCAP 96
#define ECAP 176

// sub-bucketed CSR build: 32 sub-buckets per XCD per side
#define NBKT 512
#define S_SUB 196        // ceil(6250/32)
#define E_SUB 79         // ceil(2500/32)
#define BKCAP 8704       // mean ~7850, sd ~89 -> +9.6 sigma
#define OVL_BKTS 257     // buckets 0..256 overlay statAH+kdiffAH (17.92 MB)

#define BK_BLOCKS 245    // bucketize blocks: ceil(2*NE/4 / 2048)
#define CVT_BLOCKS 4375  // (S_N+E_N)*64 / 1024
#define MARK_BLOCKS 32   // 2*B_N / 1024

typedef short bf16x8 __attribute__((ext_vector_type(8)));
typedef float f32x4 __attribute__((ext_vector_type(4)));
typedef int i32x4 __attribute__((ext_vector_type(4)));
typedef float f32x4v __attribute__((ext_vector_type(4)));
typedef unsigned u32x4 __attribute__((ext_vector_type(4)));

__device__ __forceinline__ float sigmoidf_(float v) {
    return 1.0f / (1.0f + __expf(-v));
}
__device__ __forceinline__ float tanh_fast(float v) {
    float e = __expf(2.0f * v);
    return 1.0f - 2.0f / (e + 1.0f);
}
__device__ __forceinline__ unsigned short f2bf(float v) {
    unsigned u = __float_as_uint(v);
    u += 0x7fffu + ((u >> 16) & 1u);
    return (unsigned short)(u >> 16);
}
__device__ __forceinline__ void split_bf(float v, unsigned short& hi, unsigned short& lo) {
    unsigned u = __float_as_uint(v);
    hi = (unsigned short)(u >> 16);
    float fh = __uint_as_float(u & 0xffff0000u);
    lo = f2bf(v - fh);
}
// unpack a u32 holding 2 halves
__device__ __forceinline__ float2 h2f2(unsigned u) {
    __half2 h = *(const __half2*)&u;
    return __half22float2(h);
}
// accumulate 8 halves (one uint4) scaled by v into acc[0..7]
__device__ __forceinline__ void accum8(float* acc, uint4 h, float v) {
    float2 p0 = h2f2(h.x);
    float2 p1 = h2f2(h.y);
    float2 p2 = h2f2(h.z);
    float2 p3 = h2f2(h.w);
    acc[0] = fmaf(v, p0.x, acc[0]); acc[1] = fmaf(v, p0.y, acc[1]);
    acc[2] = fmaf(v, p1.x, acc[2]); acc[3] = fmaf(v, p1.y, acc[3]);
    acc[4] = fmaf(v, p2.x, acc[4]); acc[5] = fmaf(v, p2.y, acc[5]);
    acc[6] = fmaf(v, p3.x, acc[6]); acc[7] = fmaf(v, p3.y, acc[7]);
}
__device__ __forceinline__ unsigned f2h2u(float a, float b) {
    __half2 h = __floats2half2_rn(a, b);
    return *(const unsigned*)&h;
}

__device__ __forceinline__ unsigned long long* bslot(
    unsigned long long* ovl, unsigned long long* fr, int b) {
    return (b < OVL_BKTS) ? ovl + (size_t)b * BKCAP
                          : fr + (size_t)(b - OVL_BKTS) * BKCAP;
}

// ---- R23 fused init: bucketize (blocks 0..244) || fp16 cvt || mark ------
// The three parts are mutually independent; one launch overlaps them
// (stream kernels otherwise serialize). cnt zero-init is DEAD (scatter2
// writes every node's count); masks+cur zeroed by a 14KB hipMemsetAsync.
// Bucketize: R17 structure (LDS-hist rank + one global claim per
// (block,bucket)); R18 sizing (1024 thr x 8 edges -> ~256B runs).
__global__ __launch_bounds__(1024) void build_init(
    const i32x4* __restrict__ r1, const i32x4* __restrict__ c1,
    const f32x4v* __restrict__ vui1, const f32x4v* __restrict__ viu1,
    const i32x4* __restrict__ r0, const i32x4* __restrict__ c0,
    const f32x4v* __restrict__ vui0, const f32x4v* __restrict__ viu0,
    unsigned long long* __restrict__ bOvl, unsigned long long* __restrict__ bFr,
    int* __restrict__ gcur,
    const float2* __restrict__ sE, const float2* __restrict__ eE,
    __half2* __restrict__ sH, __half2* __restrict__ eH,
    const int* __restrict__ sid, const int* __restrict__ eid,
    unsigned* __restrict__ maskS, unsigned* __restrict__ maskE) {
    const int tid = threadIdx.x;
    if ((int)blockIdx.x >= BK_BLOCKS) {
        int rel = blockIdx.x - BK_BLOCKS;
        if (rel < CVT_BLOCKS) {
            int i = rel * 1024 + tid;
            const int nS = S_N * 64;
            if (i < nS) {
                float2 v = sE[i];
                sH[i] = __floats2half2_rn(v.x, v.y);
            } else {
                int j = i - nS;
                if (j < E_N * 64) {
                    float2 v = eE[j];
                    eH[j] = __floats2half2_rn(v.x, v.y);
                }
            }
        } else {
            int i = (rel - CVT_BLOCKS) * 1024 + tid;
            if (i < B_N) {
                int v = sid[i];
                atomicOr(&maskS[v >> 5], 1u << (v & 31));
            } else if (i < 2 * B_N) {
                int v = eid[i - B_N];
                atomicOr(&maskE[v >> 5], 1u << (v & 31));
            }
        }
        return;
    }
    __shared__ int hist[NBKT];
    __shared__ int base[NBKT];
    for (int b = tid; b < NBKT; b += 1024) hist[b] = 0;
    __syncthreads();
    const int NV = NE_N / 4;          // 250000 vectors per relation
    i32x4 rv[2], cv[2]; f32x4v av[2], bv[2];
    int bkt[16], lr[16];
#pragma unroll
    for (int rep = 0; rep < 2; ++rep) {
        int i = blockIdx.x * 2048 + rep * 1024 + tid;
        bool valid = i < 2 * NV;
        if (valid) {
            if (i < NV) {
                rv[rep] = __builtin_nontemporal_load(r1 + i);
                cv[rep] = __builtin_nontemporal_load(c1 + i);
                av[rep] = __builtin_nontemporal_load(vui1 + i);
                bv[rep] = __builtin_nontemporal_load(viu1 + i);
            } else {
                int j = i - NV;
                rv[rep] = __builtin_nontemporal_load(r0 + j);
                cv[rep] = __builtin_nontemporal_load(c0 + j);
                av[rep] = __builtin_nontemporal_load(vui0 + j);
                bv[rep] = __builtin_nontemporal_load(viu0 + j);
            }
        }
#pragma unroll
        for (int k = 0; k < 4; ++k) {
            int u = rep * 8 + k * 2;
            if (valid) {
                int r = rv[rep][k], c = cv[rep][k];
                int xs = r / S_PER_XCD;
                int ss = (r - xs * S_PER_XCD) / S_SUB;
                int xe = c / E_PER_XCD;
                int se = (c - xe * E_PER_XCD) / E_SUB;
                bkt[u] = ss * 8 + xs;
                bkt[u + 1] = 256 + se * 8 + xe;
                lr[u] = atomicAdd(&hist[bkt[u]], 1);
                lr[u + 1] = atomicAdd(&hist[bkt[u + 1]], 1);
            } else {
                bkt[u] = -1; bkt[u + 1] = -1;
            }
        }
    }
    __syncthreads();
    for (int b = tid; b < NBKT; b += 1024) {
        int h = hist[b];
        base[b] = h ? atomicAdd(&gcur[b], h) : 0;
    }
    __syncthreads();
#pragma unroll
    for (int rep = 0; rep < 2; ++rep) {
#pragma unroll
        for (int k = 0; k < 4; ++k) {
            int u = rep * 8 + k * 2;
            if (bkt[u] >= 0) {
                int r = rv[rep][k], c = cv[rep][k];
                unsigned entS = ((unsigned)f2bf(av[rep][k]) << 16) | (unsigned)c;
                unsigned entE = ((unsigned)f2bf(bv[rep][k]) << 16) | (unsigned)r;
                int pS = base[bkt[u]] + lr[u];
                int pE = base[bkt[u + 1]] + lr[u + 1];
                if (pS < BKCAP)
                    bslot(bOvl, bFr, bkt[u])[pS] =
                        ((unsigned long long)(unsigned)r << 32) | entS;
                if (pE < BKCAP)
                    bslot(bOvl, bFr, bkt[u + 1])[pE] =
                        ((unsigned long long)(unsigned)c << 32) | entE;
            }
        }
    }
}

// ---- CSR build phase 2: one WG per sub-bucket, LDS slot counters --------
// Block bid -> XCD bid&7 matches the node partition, so CSR writes are
// XCD-local. Slot claim is an LDS atomic; zero global atomics. Final
// per-node counts written once (covers ALL nodes -> no zero-init needed).
// R23: 1024 threads (vs 256) for 4x fewer strided iterations.
__global__ __launch_bounds__(1024) void scatter2(
    unsigned long long* __restrict__ bOvl, unsigned long long* __restrict__ bFr,
    const int* __restrict__ gcur,
    int* __restrict__ cntS, int* __restrict__ cntE,
    unsigned* __restrict__ csrS, unsigned* __restrict__ csrE) {
    __shared__ int lcnt[S_SUB];
    const int bid = blockIdx.x;
    const int tid = threadIdx.x;
    const bool isS = bid < 256;
    const int x = bid & 7;
    const int s = (isS ? bid : bid - 256) >> 3;
    const int start = isS ? x * S_PER_XCD + s * S_SUB : x * E_PER_XCD + s * E_SUB;
    const int len = isS ? min(S_SUB, S_PER_XCD - s * S_SUB)
                        : min(E_SUB, E_PER_XCD - s * E_SUB);
    for (int l = tid; l < len; l += 1024) lcnt[l] = 0;
    __syncthreads();
    int n = gcur[bid];
    if (n > BKCAP) n = BKCAP;
    const unsigned long long* bp = bslot(bOvl, bFr, bid);
    for (int i = tid; i < n; i += 1024) {
        unsigned long long v = __builtin_nontemporal_load(bp + i);
        int node = (int)(v >> 32);
        unsigned entry = (unsigned)v;
        int slot = atomicAdd(&lcnt[node - start], 1);
        if (isS) {
            if (slot < SCAP) csrS[(size_t)node * SCAP + slot] = entry;
        } else {
            if (slot < ECAP) csrE[(size_t)node * ECAP + slot] = entry;
        }
    }
    __syncthreads();
    for (int l = tid; l < len; l += 1024) {
        if (isS) cntS[start + l] = min(lcnt[l], SCAP);
        else     cntE[start + l] = min(lcnt[l], ECAP);
    }
}

// ---- propagation row body: wave = 1 dest row; slot(lane>>4) = 1 of 4
// edges in flight, seg(lane&15) = 16 B of the 256 B row. 16 edges in
// flight (R18). NT self/dst (R21, neutral-kept).
__device__ __forceinline__ void gather_row(
    const uint4* __restrict__ src, const uint4* __restrict__ self,
    const float* __restrict__ dA, const float* __restrict__ dB,
    const int* __restrict__ cnt, const unsigned* __restrict__ csr,
    const unsigned* __restrict__ need,
    uint4* __restrict__ dst, int nrow, int cap, int w, int lane) {
    int slot = lane >> 4;
    int seg = lane & 15;
    if (w >= nrow) return;
    if (need && !((need[w >> 5] >> (w & 31)) & 1u)) return;
    int n = cnt[w];
    if (n > cap) n = cap;
    const unsigned* cbase = csr + (size_t)w * cap;
    float acc[8] = {};
    int i = 0;
    for (; i + 16 <= n; i += 16) {
        unsigned qa = __builtin_nontemporal_load(cbase + i + slot);
        unsigned qb = __builtin_nontemporal_load(cbase + i + 4 + slot);
        unsigned qc = __builtin_nontemporal_load(cbase + i + 8 + slot);
        unsigned qd = __builtin_nontemporal_load(cbase + i + 12 + slot);
        uint4 ha = src[(size_t)(qa & 0xffffu) * 16 + seg];
        uint4 hb = src[(size_t)(qb & 0xffffu) * 16 + seg];
        uint4 hc = src[(size_t)(qc & 0xffffu) * 16 + seg];
        uint4 hd = src[(size_t)(qd & 0xffffu) * 16 + seg];
        accum8(acc, ha, __uint_as_float(qa & 0xffff0000u));
        accum8(acc, hb, __uint_as_float(qb & 0xffff0000u));
        accum8(acc, hc, __uint_as_float(qc & 0xffff0000u));
        accum8(acc, hd, __uint_as_float(qd & 0xffff0000u));
    }
    for (; i + 8 <= n; i += 8) {
        unsigned qa = __builtin_nontemporal_load(cbase + i + slot);
        unsigned qb = __builtin_nontemporal_load(cbase + i + 4 + slot);
        uint4 ha = src[(size_t)(qa & 0xffffu) * 16 + seg];
        uint4 hb = src[(size_t)(qb & 0xffffu) * 16 + seg];
        accum8(acc, ha, __uint_as_float(qa & 0xffff0000u));
        accum8(acc, hb, __uint_as_float(qb & 0xffff0000u));
    }
    for (; i < n; i += 4) {
        int e = i + slot;
        if (e < n) {
            unsigned q = __builtin_nontemporal_load(cbase + e);
            uint4 h = src[(size_t)(q & 0xffffu) * 16 + seg];
            accum8(acc, h, __uint_as_float(q & 0xffff0000u));
        }
    }
#pragma unroll
    for (int j = 0; j < 8; ++j) {
        acc[j] += __shfl_xor(acc[j], 16);
        acc[j] += __shfl_xor(acc[j], 32);
    }
    if (slot == 0) {
        u32x4 hsv = __builtin_nontemporal_load(
            reinterpret_cast<const u32x4*>(self) + ((size_t)w * 16 + seg));
        unsigned h0 = hsv[0], h1 = hsv[1], h2 = hsv[2], h3 = hsv[3];
        float d = dA[w] + dB[w];
        float2 s0 = h2f2(h0);
        float2 s1 = h2f2(h1);
        float2 s2 = h2f2(h2);
        float2 s3 = h2f2(h3);
        u32x4 o;
        o[0] = f2h2u(fmaf(s0.x, d, acc[0]), fmaf(s0.y, d, acc[1]));
        o[1] = f2h2u(fmaf(s1.x, d, acc[2]), fmaf(s1.y, d, acc[3]));
        o[2] = f2h2u(fmaf(s2.x, d, acc[4]), fmaf(s2.y, d, acc[5]));
        o[3] = f2h2u(fmaf(s3.x, d, acc[6]), fmaf(s3.y, d, acc[7]));
        __builtin_nontemporal_store(
            o, reinterpret_cast<u32x4*>(dst) + ((size_t)w * 16 + seg));
    }
}

// ---- R20: fused S+E gather. E blocks first: long ~100-edge E rows start
// early, short S rows fill the tail.
__global__ __launch_bounds__(256) void gather_dual(
    const uint4* __restrict__ srcE, const uint4* __restrict__ selfE,
    const float* __restrict__ dEA, const float* __restrict__ dEB,
    const int* __restrict__ cntEp, const unsigned* __restrict__ csrEp,
    const unsigned* __restrict__ needE, uint4* __restrict__ dstE,
    const uint4* __restrict__ srcS, const uint4* __restrict__ selfS,
    const float* __restrict__ dSA, const float* __restrict__ dSB,
    const int* __restrict__ cntSp, const unsigned* __restrict__ csrSp,
    const unsigned* __restrict__ needS, uint4* __restrict__ dstS,
    int eBlocks) {
    int lane = threadIdx.x & 63;
    int sub = threadIdx.x >> 6;
    if ((int)blockIdx.x < eBlocks) {
        int w = blockIdx.x * 4 + sub;
        gather_row(srcE, selfE, dEA, dEB, cntEp, csrEp, needE, dstE,
                   E_N, ECAP, w, lane);
    } else {
        int w = (blockIdx.x - eBlocks) * 4 + sub;
        gather_row(srcS, selfS, dSA, dSB, cntSp, csrSp, needS, dstS,
                   S_N, SCAP, w, lane);
    }
}

// ---- prediction stage 1+0 fused: feature x -> split bf16, and |W| ->
// split bf16 tables (blocks >= featBlocks). (R21)
__global__ __launch_bounds__(256) void feature_abs_kernel(
    const int* __restrict__ stu_id, const int* __restrict__ ex_id,
    const float* __restrict__ ikp,
    const __half2* __restrict__ statH, const __half2* __restrict__ kdiffH,
    const float* __restrict__ s_bias, const float* __restrict__ e_disc,
    unsigned short* __restrict__ xhi, unsigned short* __restrict__ xlo,
    const float* __restrict__ W1, const float* __restrict__ W2,
    unsigned short* __restrict__ w1hi, unsigned short* __restrict__ w1lo,
    unsigned short* __restrict__ w2hi, unsigned short* __restrict__ w2lo,
    int featBlocks) {
    if ((int)blockIdx.x >= featBlocks) {
        int i = (blockIdx.x - featBlocks) * 256 + threadIdx.x;
        unsigned short hi, lo;
        if (i < 32768) {
            split_bf(fabsf(W1[i]), hi, lo);
            w1hi[i] = hi; w1lo[i] = lo;
        } else {
            int j = i - 32768;
            split_bf(fabsf(W2[j]), hi, lo);
            w2hi[j] = hi; w2lo[j] = lo;
        }
        return;
    }
    int i = blockIdx.x * 256 + threadIdx.x;
    int row = i >> 5;
    int k4 = (i & 31) * 4;
    int s = stu_id[row];
    int e = ex_id[row];
    float sb = s_bias[s];
    float ed = sigmoidf_(e_disc[e]);
    float2 s01 = __half22float2(statH[(size_t)s * 64 + (k4 >> 1)]);
    float2 s23 = __half22float2(statH[(size_t)s * 64 + (k4 >> 1) + 1]);
    float2 k01 = __half22float2(kdiffH[(size_t)e * 64 + (k4 >> 1)]);
    float2 k23 = __half22float2(kdiffH[(size_t)e * 64 + (k4 >> 1) + 1]);
    float4 iv = *(const float4*)(ikp + (size_t)row * K_N + k4);
    float f0 = iv.x * (sigmoidf_(s01.x + sb) - sigmoidf_(k01.x)) * ed;
    float f1 = iv.y * (sigmoidf_(s01.y + sb) - sigmoidf_(k01.y)) * ed;
    float f2 = iv.z * (sigmoidf_(s23.x + sb) - sigmoidf_(k23.x)) * ed;
    float f3 = iv.w * (sigmoidf_(s23.y + sb) - sigmoidf_(k23.y)) * ed;
    ushort4 oh, ol;
    split_bf(f0, oh.x, ol.x);
    split_bf(f1, oh.y, ol.y);
    split_bf(f2, oh.z, ol.z);
    split_bf(f3, oh.w, ol.w);
    *(ushort4*)(xhi + (size_t)row * K_N + k4) = oh;
    *(ushort4*)(xlo + (size_t)row * K_N + k4) = ol;
}

// ---- prediction stage 2: split-bf16 MFMA MLP ----------------------------
#define H1S 264

__global__ __launch_bounds__(256) void mlp_mfma(
    const unsigned short* __restrict__ xhi, const unsigned short* __restrict__ xlo,
    const unsigned short* __restrict__ w1hi, const unsigned short* __restrict__ w1lo,
    const unsigned short* __restrict__ w2hi, const unsigned short* __restrict__ w2lo,
    const float* __restrict__ b1, const float* __restrict__ b2,
    const float* __restrict__ W3, const float* __restrict__ b3,
    float* __restrict__ out) {
    __shared__ unsigned short h1hi[32 * H1S];
    __shared__ unsigned short h1lo[32 * H1S];
    __shared__ float partial[4][32];

    const int t = threadIdx.x;
    const int lane = t & 63;
    const int w = t >> 6;
    const int l15 = lane & 15;
    const int quad = lane >> 4;
    const int r0 = blockIdx.x * 32;

    f32x4 acc1[2][4] = {};
    for (int ks = 0; ks < 128; ks += 32) {
        bf16x8 ah[2], al[2], bh[4], bl[4];
#pragma unroll
        for (int mt = 0; mt < 2; ++mt) {
            size_t o = (size_t)(r0 + mt * 16 + l15) * K_N + ks + quad * 8;
            ah[mt] = *(const bf16x8*)(xhi + o);
            al[mt] = *(const bf16x8*)(xlo + o);
        }
#pragma unroll
        for (int nt = 0; nt < 4; ++nt) {
            size_t o = (size_t)(w * 64 + nt * 16 + l15) * 128 + ks + quad * 8;
            bh[nt] = *(const bf16x8*)(w1hi + o);
            bl[nt] = *(const bf16x8*)(w1lo + o);
        }
#pragma unroll
        for (int mt = 0; mt < 2; ++mt)
#pragma unroll
            for (int nt = 0; nt < 4; ++nt) {
                acc1[mt][nt] = __builtin_amdgcn_mfma_f32_16x16x32_bf16(
                    ah[mt], bh[nt], acc1[mt][nt], 0, 0, 0);
                acc1[mt][nt] = __builtin_amdgcn_mfma_f32_16x16x32_bf16(
                    ah[mt], bl[nt], acc1[mt][nt], 0, 0, 0);
                acc1[mt][nt] = __builtin_amdgcn_mfma_f32_16x16x32_bf16(
                    al[mt], bh[nt], acc1[mt][nt], 0, 0, 0);
            }
    }
#pragma unroll
    for (int nt = 0; nt < 4; ++nt) {
        int c = w * 64 + nt * 16 + l15;
        float bias = b1[c];
#pragma unroll
        for (int mt = 0; mt < 2; ++mt)
#pragma unroll
            for (int rg = 0; rg < 4; ++rg) {
                int row = mt * 16 + quad * 4 + rg;
                float h = tanh_fast(acc1[mt][nt][rg] + bias);
                unsigned short hi, lo;
                split_bf(h, hi, lo);
                h1hi[row * H1S + c] = hi;
                h1lo[row * H1S + c] = lo;
            }
    }
    __syncthreads();

    f32x4 acc2[2][2] = {};
    for (int ks = 0; ks < 256; ks += 32) {
        bf16x8 ah[2], al[2], bh[2], bl[2];
#pragma unroll
        for (int mt = 0; mt < 2; ++mt) {
            int o = (mt * 16 + l15) * H1S + ks + quad * 8;
            ah[mt] = *(const bf16x8*)(&h1hi[o]);
            al[mt] = *(const bf16x8*)(&h1lo[o]);
        }
#pragma unroll
        for (int nt = 0; nt < 2; ++nt) {
            size_t o = (size_t)(w * 32 + nt * 16 + l15) * 256 + ks + quad * 8;
            bh[nt] = *(const bf16x8*)(w2hi + o);
            bl[nt] = *(const bf16x8*)(w2lo + o);
        }
#pragma unroll
        for (int mt = 0; mt < 2; ++mt)
#pragma unroll
            for (int nt = 0; nt < 2; ++nt) {
                acc2[mt][nt] = __builtin_amdgcn_mfma_f32_16x16x32_bf16(
                    ah[mt], bh[nt], acc2[mt][nt], 0, 0, 0);
                acc2[mt][nt] = __builtin_amdgcn_mfma_f32_16x16x32_bf16(
                    ah[mt], bl[nt], acc2[mt][nt], 0, 0, 0);
                acc2[mt][nt] = __builtin_amdgcn_mfma_f32_16x16x32_bf16(
                    al[mt], bh[nt], acc2[mt][nt], 0, 0, 0);
            }
    }

    float w3v[2], b2v[2];
#pragma unroll
    for (int nt = 0; nt < 2; ++nt) {
        int c = w * 32 + nt * 16 + l15;
        w3v[nt] = fabsf(W3[c]);
        b2v[nt] = b2[c];
    }
#pragma unroll
    for (int mt = 0; mt < 2; ++mt)
#pragma unroll
        for (int rg = 0; rg < 4; ++rg) {
            float v = w3v[0] * tanh_fast(acc2[mt][0][rg] + b2v[0]) +
                      w3v[1] * tanh_fast(acc2[mt][1][rg] + b2v[1]);
            v += __shfl_xor(v, 1, 16);
            v += __shfl_xor(v, 2, 16);
            v += __shfl_xor(v, 4, 16);
            v += __shfl_xor(v, 8, 16);
            if (l15 == 0) partial[w][mt * 16 + quad * 4 + rg] = v;
        }
    __syncthreads();
    if (t < 32) {
        float v = partial[0][t] + partial[1][t] + partial[2][t] + partial[3][t];
        out[r0 + t] = sigmoidf_(v + b3[0]);
    }
}

extern "C" void kernel_launch(void* const* d_in, const int* in_sizes, int n_in,
                              void* d_out, int out_size, void* d_ws, size_t ws_size,
                              hipStream_t stream) {
    const int* stu_id        = (const int*)d_in[0];
    const int* input_ex      = (const int*)d_in[1];
    const float* ikp         = (const float*)d_in[2];
    const int* rows_1        = (const int*)d_in[3];
    const int* cols_1        = (const int*)d_in[4];
    const int* rows_0        = (const int*)d_in[5];
    const int* cols_0        = (const int*)d_in[6];
    const float* vals_ui_1   = (const float*)d_in[7];
    const float* vals_iu_1   = (const float*)d_in[8];
    const float* vals_ui_0   = (const float*)d_in[9];
    const float* vals_iu_0   = (const float*)d_in[10];
    const float* d_i_1       = (const float*)d_in[11];
    const float* d_j_1       = (const float*)d_in[12];
    const float* d_i_0       = (const float*)d_in[13];
    const float* d_j_0       = (const float*)d_in[14];
    const float* student_emb = (const float*)d_in[15];
    const float* exercise_emb= (const float*)d_in[16];
    const float* s_bias      = (const float*)d_in[17];
    const float* e_disc      = (const float*)d_in[18];
    const float* W1          = (const float*)d_in[19];
    const float* b1          = (const float*)d_in[20];
    const float* W2          = (const float*)d_in[21];
    const float* b2          = (const float*)d_in[22];
    const float* W3          = (const float*)d_in[23];
    const float* b3          = (const float*)d_in[24];

    // ---- workspace layout (fp16 tables, 4 B packed padded CSR) ----
    char* p = (char*)d_ws;
    __half2* sEH     = (__half2*)p; p += (size_t)S_N * K_N * 2;   // inputs; reused as statBH
    __half2* eEH     = (__half2*)p; p += (size_t)E_N * K_N * 2;   // inputs; reused as kdiffBH
    __half2* statAH  = (__half2*)p; p += (size_t)S_N * K_N * 2;   // also xhi/xlo + bucket overlay
    __half2* kdiffAH = (__half2*)p; p += (size_t)E_N * K_N * 2;   // also weights + bucket overlay
    unsigned* csrS = (unsigned*)p; p += (size_t)S_N * SCAP * 4;   // 19.2 MB
    unsigned* csrE = (unsigned*)p; p += (size_t)E_N * ECAP * 4;   // 14.1 MB
    int* cntS     = (int*)p;   p += (size_t)S_N * 4;
    int* cntE     = (int*)p;   p += (size_t)E_N * 4;
    unsigned* maskS = (unsigned*)p; p += 2048 * 4;
    unsigned* maskE = (unsigned*)p; p += 1024 * 4;
    int* cur      = (int*)p;   p += NBKT * 4;
    p = (char*)(((size_t)p + 255) & ~(size_t)255);
    unsigned long long* buckFr = (unsigned long long*)p;          // buckets 257..511 (17.8 MB fresh)
    p += (size_t)(NBKT - OVL_BKTS) * BKCAP * 8;
    unsigned long long* buckOvl = (unsigned long long*)statAH;    // buckets 0..256 (17.9 MB overlay)
    __half2* statBH  = sEH;
    __half2* kdiffBH = eEH;
    unsigned short* xhi = (unsigned short*)statAH;
    unsigned short* xlo = xhi + (size_t)B_N * K_N;
    unsigned short* w1hi = (unsigned short*)kdiffAH;
    unsigned short* w1lo = w1hi + 32768;
    unsigned short* w2hi = w1lo + 32768;
    unsigned short* w2lo = w2hi + 32768;

    // ---- zero masks + bucket cursors (cnt zero-init is dead: scatter2
    // writes every node's count). maskS/maskE/cur are contiguous: 14 KB.
    hipMemsetAsync(maskS, 0, (2048 + 1024 + NBKT) * 4, stream);

    // ---- fused init: bucketize (245 blocks) || fp16 cvt || mark ----
    build_init<<<BK_BLOCKS + CVT_BLOCKS + MARK_BLOCKS, 1024, 0, stream>>>(
        (const i32x4*)rows_1, (const i32x4*)cols_1,
        (const f32x4v*)vals_ui_1, (const f32x4v*)vals_iu_1,
        (const i32x4*)rows_0, (const i32x4*)cols_0,
        (const f32x4v*)vals_ui_0, (const f32x4v*)vals_iu_0,
        buckOvl, buckFr, cur,
        (const float2*)student_emb, (const float2*)exercise_emb, sEH, eEH,
        stu_id, input_ex, maskS, maskE);

    // ---- CSR build phase 2: per-sub-bucket LDS scatter ----
    scatter2<<<NBKT, 1024, 0, stream>>>(
        buckOvl, buckFr, cur, cntS, cntE, csrS, csrE);

    const int sGrid = (S_N + 3) / 4;    // 12500
    const int eGrid = (E_N + 3) / 4;    // 5000

    // ---- layer 1: fused E+S gather (independent sides, one launch) ----
    gather_dual<<<eGrid + sGrid, 256, 0, stream>>>(
        (const uint4*)sEH, (const uint4*)eEH, d_j_1, d_j_0,
        cntE, csrE, nullptr, (uint4*)kdiffAH,
        (const uint4*)eEH, (const uint4*)sEH, d_i_1, d_i_0,
        cntS, csrS, nullptr, (uint4*)statAH, eGrid);

    // ---- layer 2: fused E+S gather (masked; inputs dead now) ----
    gather_dual<<<eGrid + sGrid, 256, 0, stream>>>(
        (const uint4*)statAH, (const uint4*)kdiffAH, d_j_1, d_j_0,
        cntE, csrE, maskE, (uint4*)kdiffBH,
        (const uint4*)kdiffAH, (const uint4*)statAH, d_i_1, d_i_0,
        cntS, csrS, maskS, (uint4*)statBH, eGrid);

    // ---- prediction: fused feature+abs -> split bf16, MFMA MLP ----
    const int featBlocks = B_N * 32 / 256;   // 2048
    feature_abs_kernel<<<featBlocks + 256, 256, 0, stream>>>(
        stu_id, input_ex, ikp, statBH, kdiffBH, s_bias, e_disc, xhi, xlo,
        W1, W2, w1hi, w1lo, w2hi, w2lo, featBlocks);
    mlp_mfma<<<B_N / 32, 256, 0, stream>>>(xhi, xlo, w1hi, w1lo, w2hi, w2lo,
                                           b1, b2, W3, b3, (float*)d_out);
}